// Round 1
// baseline (179.800 us; speedup 1.0000x reference)
//
#include <hip/hip_runtime.h>

// Problem constants (from reference)
#define NNZ_TOT     2097152
#define N_CELLS     4096
#define NUM_HID     128
#define CHUNK       256      // nnz per 32-lane group

// Each 32-lane group processes a contiguous CHUNK of nnz entries.
// Lane layout: sub = lane&31 owns hidden dims [sub*4, sub*4+4) as a float4.
// Rows are sorted -> register-accumulate, atomicAdd flush on row change.
__global__ __launch_bounds__(256) void omics_spmm_kernel(
    const float* __restrict__ xv,   // [NNZ] values
    const int*   __restrict__ xr,   // [NNZ] rows (sorted)
    const int*   __restrict__ xc,   // [NNZ] cols
    const int*   __restrict__ gidx, // [N_INPUT_GENES] gene -> embedding row
    const float* __restrict__ embs, // [N_PRETRAINED, 128]
    float*       __restrict__ out)  // [N_CELLS, 128]
{
    const int tid  = blockIdx.x * blockDim.x + threadIdx.x;
    const int wave = tid >> 6;
    const int lane = threadIdx.x & 63;
    const int sub  = lane & 31;
    const int grp  = lane >> 5;

    const long gbase = ((long)wave * 2 + grp) * CHUNK;
    const int  h4    = sub * 4;

    float4 acc = make_float4(0.f, 0.f, 0.f, 0.f);
    int cur_row = -1;

    for (int it = 0; it < CHUNK; it += 32) {
        const long i = gbase + it + sub;
        // Coalesced preload of 32 nnz triples per group
        const float v = xv[i];
        const int   r = xr[i];
        const int   g = gidx[xc[i]];

        #pragma unroll
        for (int j = 0; j < 32; ++j) {
            const float vj = __shfl(v, j, 32);
            const int   rj = __shfl(r, j, 32);
            const int   gj = __shfl(g, j, 32);

            if (rj != cur_row) {
                if (cur_row >= 0) {
                    float* o = &out[(long)cur_row * NUM_HID + h4];
                    atomicAdd(o + 0, acc.x);
                    atomicAdd(o + 1, acc.y);
                    atomicAdd(o + 2, acc.z);
                    atomicAdd(o + 3, acc.w);
                }
                cur_row = rj;
                acc = make_float4(0.f, 0.f, 0.f, 0.f);
            }

            // Coalesced 512B row read across the 32-lane group
            const float4 f = *reinterpret_cast<const float4*>(
                &embs[(long)gj * NUM_HID + h4]);
            acc.x = fmaf(vj, f.x, acc.x);
            acc.y = fmaf(vj, f.y, acc.y);
            acc.z = fmaf(vj, f.z, acc.z);
            acc.w = fmaf(vj, f.w, acc.w);
        }
    }

    if (cur_row >= 0) {
        float* o = &out[(long)cur_row * NUM_HID + h4];
        atomicAdd(o + 0, acc.x);
        atomicAdd(o + 1, acc.y);
        atomicAdd(o + 2, acc.z);
        atomicAdd(o + 3, acc.w);
    }
}

extern "C" void kernel_launch(void* const* d_in, const int* in_sizes, int n_in,
                              void* d_out, int out_size, void* d_ws, size_t ws_size,
                              hipStream_t stream) {
    const float* xv   = (const float*)d_in[0];
    const int*   xr   = (const int*)  d_in[1];
    const int*   xc   = (const int*)  d_in[2];
    const int*   gidx = (const int*)  d_in[3];
    const float* embs = (const float*)d_in[4];
    float*       out  = (float*)d_out;

    // Harness poisons d_out with 0xAA before every launch; we accumulate with
    // atomics, so zero it first (hipMemsetAsync is graph-capture safe).
    hipMemsetAsync(out, 0, (size_t)out_size * sizeof(float), stream);

    // total 32-lane groups = NNZ / CHUNK = 8192 -> waves = 4096 -> blocks = 1024
    const int n_groups = NNZ_TOT / CHUNK;
    const int n_waves  = n_groups / 2;
    const int blocks   = n_waves / 4;       // 4 waves (256 thr) per block
    omics_spmm_kernel<<<blocks, 256, 0, stream>>>(xv, xr, xc, gidx, embs, out);
}